// Round 1
// baseline (1136.812 us; speedup 1.0000x reference)
//
#include <hip/hip_runtime.h>
#include <hip/hip_bf16.h>
#include <stdint.h>

typedef __attribute__((ext_vector_type(8))) short bf16x8;
typedef __attribute__((ext_vector_type(4))) float f32x4;
typedef __attribute__((ext_vector_type(4))) unsigned short u16x4;

__device__ __forceinline__ unsigned short f2b(float x) {
  __hip_bfloat16 h = __float2bfloat16(x);
  unsigned short u;
  __builtin_memcpy(&u, &h, 2);
  return u;
}

__device__ __forceinline__ void glds16(const void* g, void* l) {
  __builtin_amdgcn_global_load_lds((const __attribute__((address_space(1))) void*)g,
                                   (__attribute__((address_space(3))) void*)l,
                                   16, 0, 0);
}

__device__ __forceinline__ float wred_add(float v) {
#pragma unroll
  for (int o = 32; o >= 1; o >>= 1) v += __shfl_xor(v, o, 64);
  return v;
}
__device__ __forceinline__ float wred_max(float v) {
#pragma unroll
  for (int o = 32; o >= 1; o >>= 1) v = fmaxf(v, __shfl_xor(v, o, 64));
  return v;
}

// ---------------------------------------------------------------------------
// NT GEMM: out[m,n] = (sum_k A[m,k]*Bt[n,k] + bias[n]) * scale
// A: [M,K] bf16 row-major, Bt: [N,K] bf16 row-major. 128x128 tile, BK=32,
// 256 threads = 4 waves (2x2), each wave 64x64 via 4x4 frags of 16x16x32 MFMA.
// MODE 0: bf16 out [M,N]     MODE 1: bf16 transposed per-batch ([B][N][npos])
// MODE 2: f32 out            MODE 3: f32 out + resid add
// ---------------------------------------------------------------------------
template <int MODE>
__global__ __launch_bounds__(256) void gemm_nt(
    const unsigned short* __restrict__ A, int lda, long long sA,
    const unsigned short* __restrict__ Bt, int ldb, long long sB,
    void* __restrict__ C, int ldc, long long sC,
    int K, const float* __restrict__ bias, float scale,
    const float* __restrict__ resid, int npos)
{
  __shared__ unsigned short As[128 * 32];
  __shared__ unsigned short Bs[128 * 32];
  const int t = threadIdx.x;
  const int lane = t & 63;
  const int wv_ = t >> 6;
  const int wr = wv_ >> 1, wc = wv_ & 1;
  const int z = blockIdx.z;
  const long long row0 = (long long)blockIdx.y * 128;
  const long long col0 = (long long)blockIdx.x * 128;
  A += (long long)z * sA;
  Bt += (long long)z * sB;

  // staging: thread t loads 16B: row = t/4 (+64 for 2nd inst), col8 = (t%4)*8
  const int sr = t >> 2;
  const int sc = (t & 3) * 8;
  const unsigned short* ga = A + (row0 + sr) * lda + sc;
  const unsigned short* gb = Bt + (col0 + sr) * ldb + sc;
  char* lA = (char*)As + (t >> 6) * 1024;  // wave-uniform LDS base
  char* lB = (char*)Bs + (t >> 6) * 1024;

  const int l15 = lane & 15;
  const int l4 = lane >> 4;
  const unsigned short* pa = As + (wr * 64 + l15) * 32 + l4 * 8;
  const unsigned short* pb = Bs + (wc * 64 + l15) * 32 + l4 * 8;

  f32x4 acc[4][4] = {};

  for (int k0 = 0; k0 < K; k0 += 32) {
    glds16(ga, lA);
    glds16(ga + 64 * lda, lA + 4096);
    glds16(gb, lB);
    glds16(gb + 64 * ldb, lB + 4096);
    ga += 32;
    gb += 32;
    __syncthreads();  // compiler drains vmcnt before s_barrier
    bf16x8 a[4], b[4];
#pragma unroll
    for (int i = 0; i < 4; i++) a[i] = *(const bf16x8*)(pa + i * 512);
#pragma unroll
    for (int j = 0; j < 4; j++) b[j] = *(const bf16x8*)(pb + j * 512);
#pragma unroll
    for (int i = 0; i < 4; i++)
#pragma unroll
      for (int j = 0; j < 4; j++)
        acc[i][j] = __builtin_amdgcn_mfma_f32_16x16x32_bf16(a[i], b[j], acc[i][j], 0, 0, 0);
    __syncthreads();
  }

  // epilogue: C/D layout col = lane&15, row = (lane>>4)*4 + reg  [m89/m91]
  const long long zoff = (long long)z * sC;
#pragma unroll
  for (int i = 0; i < 4; i++) {
#pragma unroll
    for (int j = 0; j < 4; j++) {
      const int col = (int)col0 + wc * 64 + j * 16 + l15;
      const float bv_ = bias ? bias[col] : 0.f;
#pragma unroll
      for (int r = 0; r < 4; r++) {
        const int row = (int)row0 + wr * 64 + i * 16 + l4 * 4 + r;
        const float val = (acc[i][j][r] + bv_) * scale;
        if constexpr (MODE == 0) {
          ((unsigned short*)C)[zoff + (long long)row * ldc + col] = f2b(val);
        } else if constexpr (MODE == 1) {
          const int bb = row / npos, rr = row - bb * npos;
          const int Nc = (int)gridDim.x * 128;
          ((unsigned short*)C)[((long long)bb * Nc + col) * npos + rr] = f2b(val);
        } else if constexpr (MODE == 2) {
          ((float*)C)[zoff + (long long)row * ldc + col] = val;
        } else {
          const long long idx = (long long)row * ldc + col;
          ((float*)C)[idx] = resid[idx] + val;
        }
      }
    }
  }
}

// ---------------------------------------------------------------------------
// LayerNorm over C=256, one row per block (256 threads), fp32 in -> bf16 out
// ---------------------------------------------------------------------------
__global__ __launch_bounds__(256) void ln_bf16(const float* __restrict__ x,
                                               const float* __restrict__ gamma,
                                               const float* __restrict__ beta,
                                               unsigned short* __restrict__ h)
{
  const long long row = blockIdx.x;
  const float* xr = x + row * 256;
  const int t = threadIdx.x;
  const float v = xr[t];
  float s = wred_add(v);
  float s2 = wred_add(v * v);
  __shared__ float red[8];
  const int w = t >> 6, lane = t & 63;
  if (lane == 0) { red[w] = s; red[4 + w] = s2; }
  __syncthreads();
  s = red[0] + red[1] + red[2] + red[3];
  s2 = red[4] + red[5] + red[6] + red[7];
  const float mean = s * (1.f / 256.f);
  const float var = s2 * (1.f / 256.f) - mean * mean;
  const float rstd = rsqrtf(var + 1e-3f);
  h[row * 256 + t] = f2b((v - mean) * rstd * gamma[t] + beta[t]);
}

// ---------------------------------------------------------------------------
// Row softmax: S fp32 [4096] -> P bf16 [4096], one row per block
// ---------------------------------------------------------------------------
__global__ __launch_bounds__(256) void softmax_row(const float* __restrict__ S,
                                                   unsigned short* __restrict__ P)
{
  const long long row = blockIdx.x;
  const float* s = S + row * 4096;
  unsigned short* p = P + row * 4096;
  const int t = threadIdx.x;
  f32x4 v[4];
#pragma unroll
  for (int c = 0; c < 4; c++) v[c] = ((const f32x4*)s)[t + 256 * c];
  float m = -3.0e38f;
#pragma unroll
  for (int c = 0; c < 4; c++)
#pragma unroll
    for (int e = 0; e < 4; e++) m = fmaxf(m, v[c][e]);
  m = wred_max(m);
  __shared__ float red[8];
  const int w = t >> 6, lane = t & 63;
  if (lane == 0) red[w] = m;
  __syncthreads();
  m = fmaxf(fmaxf(red[0], red[1]), fmaxf(red[2], red[3]));
  float sum = 0.f;
#pragma unroll
  for (int c = 0; c < 4; c++)
#pragma unroll
    for (int e = 0; e < 4; e++) {
      const float ev = exp2f((v[c][e] - m) * 1.44269504f);
      v[c][e] = ev;
      sum += ev;
    }
  sum = wred_add(sum);
  if (lane == 0) red[4 + w] = sum;
  __syncthreads();
  sum = red[4] + red[5] + red[6] + red[7];
  const float inv = 1.f / sum;
#pragma unroll
  for (int c = 0; c < 4; c++) {
    u16x4 u;
#pragma unroll
    for (int e = 0; e < 4; e++) u[e] = f2b(v[c][e] * inv);
    ((u16x4*)p)[t + 256 * c] = u;
  }
}

// ---------------------------------------------------------------------------
// Transpose + bf16-cast the four 256x256 weights: wT[z][n][k] = bf16(w[z][k][n])
// ---------------------------------------------------------------------------
__global__ void wtrans(const float* __restrict__ wq, const float* __restrict__ wk,
                       const float* __restrict__ wv, const float* __restrict__ wo,
                       unsigned short* __restrict__ wT)
{
  const float* w = blockIdx.z == 0 ? wq : blockIdx.z == 1 ? wk : blockIdx.z == 2 ? wv : wo;
  unsigned short* o = wT + (long long)blockIdx.z * 65536;
  __shared__ float tile[16][17];
  const int tx = threadIdx.x, ty = threadIdx.y;
  const int bx = blockIdx.x * 16, by = blockIdx.y * 16;
  tile[ty][tx] = w[(by + ty) * 256 + bx + tx];
  __syncthreads();
  o[(bx + ty) * 256 + (by + tx)] = f2b(tile[tx][ty]);
}

// ---------------------------------------------------------------------------
extern "C" void kernel_launch(void* const* d_in, const int* in_sizes, int n_in,
                              void* d_out, int out_size, void* d_ws, size_t ws_size,
                              hipStream_t stream)
{
  const float* x = (const float*)d_in[0];
  const float* gamma = (const float*)d_in[1];
  const float* beta = (const float*)d_in[2];
  const float* wq = (const float*)d_in[3];
  const float* bq = (const float*)d_in[4];
  const float* wk = (const float*)d_in[5];
  const float* bk = (const float*)d_in[6];
  const float* wv = (const float*)d_in[7];
  const float* bv = (const float*)d_in[8];
  const float* wo = (const float*)d_in[9];
  const float* bo = (const float*)d_in[10];

  const int Bn = 8, Np = 4096, Cc = 256;
  const long long MR = (long long)Bn * Np;  // 32768

  char* base = (char*)d_ws;
  size_t off = 0;
  auto take = [&](size_t bytes) -> char* {
    char* p = base + off;
    off = (off + bytes + 255) & ~(size_t)255;
    return p;
  };
  unsigned short* h  = (unsigned short*)take((size_t)MR * Cc * 2);   // LN out, bf16
  unsigned short* q  = (unsigned short*)take((size_t)MR * Cc * 2);   // bf16, pre-scaled 1/16
  unsigned short* kk = (unsigned short*)take((size_t)MR * Cc * 2);   // bf16
  unsigned short* vT = (unsigned short*)take((size_t)MR * Cc * 2);   // bf16 [B][C][Np]
  unsigned short* oo = (unsigned short*)take((size_t)MR * Cc * 2);   // attn out bf16
  unsigned short* wT = (unsigned short*)take(4ull * Cc * Cc * 2);    // 4 transposed weights
  float* S = (float*)take((size_t)Np * Np * 4);                      // scores fp32, per-batch reuse
  const size_t needA = off + (size_t)Bn * Np * Np * 2;
  const bool pathA = (ws_size >= needA);  // P for all batches -> one z-batched PV
  unsigned short* P = (unsigned short*)take(pathA ? (size_t)Bn * Np * Np * 2
                                                  : (size_t)Np * Np * 2);

  wtrans<<<dim3(16, 16, 4), dim3(16, 16), 0, stream>>>(wq, wk, wv, wo, wT);
  ln_bf16<<<dim3((unsigned)MR), dim3(256), 0, stream>>>(x, gamma, beta, h);

  // Q = (h@wq + bq)/sqrt(C) ; K = h@wk + bk ; V stored transposed per batch
  gemm_nt<0><<<dim3(2, 256, 1), 256, 0, stream>>>(h, Cc, 0, wT + 0 * 65536, Cc, 0,
                                                  q, Cc, 0, Cc, bq, 0.0625f, nullptr, 0);
  gemm_nt<0><<<dim3(2, 256, 1), 256, 0, stream>>>(h, Cc, 0, wT + 1 * 65536, Cc, 0,
                                                  kk, Cc, 0, Cc, bk, 1.0f, nullptr, 0);
  gemm_nt<1><<<dim3(2, 256, 1), 256, 0, stream>>>(h, Cc, 0, wT + 2 * 65536, Cc, 0,
                                                  vT, 0, 0, Cc, bv, 1.0f, nullptr, Np);

  for (int b = 0; b < Bn; b++) {
    gemm_nt<2><<<dim3(32, 32, 1), 256, 0, stream>>>(
        q + (long long)b * Np * Cc, Cc, 0,
        kk + (long long)b * Np * Cc, Cc, 0,
        S, Np, 0, Cc, nullptr, 1.0f, nullptr, 0);
    unsigned short* Pb = pathA ? P + (long long)b * Np * Np : P;
    softmax_row<<<dim3(Np), dim3(256), 0, stream>>>(S, Pb);
    if (!pathA) {
      gemm_nt<0><<<dim3(2, 32, 1), 256, 0, stream>>>(
          Pb, Np, 0, vT + (long long)b * Cc * Np, Np, 0,
          oo + (long long)b * Np * Cc, Cc, 0, Np, nullptr, 1.0f, nullptr, 0);
    }
  }
  if (pathA) {
    gemm_nt<0><<<dim3(2, 32, 8), 256, 0, stream>>>(
        P, Np, (long long)Np * Np, vT, Np, (long long)Cc * Np,
        oo, Cc, (long long)Np * Cc, Np, nullptr, 1.0f, nullptr, 0);
  }

  // out = x + oo@wo + bo
  gemm_nt<3><<<dim3(2, 256, 1), 256, 0, stream>>>(oo, Cc, 0, wT + 3 * 65536, Cc, 0,
                                                  (float*)d_out, Cc, 0, Cc, bo, 1.0f, x, 0);
}

// Round 2
// 450.527 us; speedup vs baseline: 2.5233x; 2.5233x over previous
//
#include <hip/hip_runtime.h>
#include <hip/hip_bf16.h>
#include <stdint.h>

typedef __attribute__((ext_vector_type(8))) short bf16x8;
typedef __attribute__((ext_vector_type(4))) float f32x4;
typedef __attribute__((ext_vector_type(4))) unsigned short u16x4;

__device__ __forceinline__ unsigned short f2b(float x) {
  __hip_bfloat16 h = __float2bfloat16(x);
  unsigned short u;
  __builtin_memcpy(&u, &h, 2);
  return u;
}

__device__ __forceinline__ void glds16(const void* g, void* l) {
  __builtin_amdgcn_global_load_lds((const __attribute__((address_space(1))) void*)g,
                                   (__attribute__((address_space(3))) void*)l,
                                   16, 0, 0);
}

__device__ __forceinline__ float wred_add(float v) {
#pragma unroll
  for (int o = 32; o >= 1; o >>= 1) v += __shfl_xor(v, o, 64);
  return v;
}

// ---------------------------------------------------------------------------
// NT GEMM (m97 structure): out[m,n] = (sum_k A[m,k]*Bt[n,k] + bias[n]) * scale
// MODE 0: bf16 out   MODE 1: bf16 transposed per-batch   MODE 3: f32 + resid
// ---------------------------------------------------------------------------
template <int MODE>
__global__ __launch_bounds__(256) void gemm_nt(
    const unsigned short* __restrict__ A, int lda, long long sA,
    const unsigned short* __restrict__ Bt, int ldb, long long sB,
    void* __restrict__ C, int ldc, long long sC,
    int K, const float* __restrict__ bias, float scale,
    const float* __restrict__ resid, int npos)
{
  __shared__ unsigned short As[128 * 32];
  __shared__ unsigned short Bs[128 * 32];
  const int t = threadIdx.x;
  const int lane = t & 63;
  const int wv_ = t >> 6;
  const int wr = wv_ >> 1, wc = wv_ & 1;
  const int z = blockIdx.z;
  const long long row0 = (long long)blockIdx.y * 128;
  const long long col0 = (long long)blockIdx.x * 128;
  A += (long long)z * sA;
  Bt += (long long)z * sB;

  const int sr = t >> 2;
  const int sc = (t & 3) * 8;
  const unsigned short* ga = A + (row0 + sr) * lda + sc;
  const unsigned short* gb = Bt + (col0 + sr) * ldb + sc;
  char* lA = (char*)As + (t >> 6) * 1024;
  char* lB = (char*)Bs + (t >> 6) * 1024;

  const int l15 = lane & 15;
  const int l4 = lane >> 4;
  const unsigned short* pa = As + (wr * 64 + l15) * 32 + l4 * 8;
  const unsigned short* pb = Bs + (wc * 64 + l15) * 32 + l4 * 8;

  f32x4 acc[4][4] = {};

  for (int k0 = 0; k0 < K; k0 += 32) {
    glds16(ga, lA);
    glds16(ga + 64 * lda, lA + 4096);
    glds16(gb, lB);
    glds16(gb + 64 * ldb, lB + 4096);
    ga += 32;
    gb += 32;
    __syncthreads();
    bf16x8 a[4], b[4];
#pragma unroll
    for (int i = 0; i < 4; i++) a[i] = *(const bf16x8*)(pa + i * 512);
#pragma unroll
    for (int j = 0; j < 4; j++) b[j] = *(const bf16x8*)(pb + j * 512);
#pragma unroll
    for (int i = 0; i < 4; i++)
#pragma unroll
      for (int j = 0; j < 4; j++)
        acc[i][j] = __builtin_amdgcn_mfma_f32_16x16x32_bf16(a[i], b[j], acc[i][j], 0, 0, 0);
    __syncthreads();
  }

  const long long zoff = (long long)z * sC;
#pragma unroll
  for (int i = 0; i < 4; i++) {
#pragma unroll
    for (int j = 0; j < 4; j++) {
      const int col = (int)col0 + wc * 64 + j * 16 + l15;
      const float bv_ = bias ? bias[col] : 0.f;
#pragma unroll
      for (int r = 0; r < 4; r++) {
        const int row = (int)row0 + wr * 64 + i * 16 + l4 * 4 + r;
        const float val = (acc[i][j][r] + bv_) * scale;
        if constexpr (MODE == 0) {
          ((unsigned short*)C)[zoff + (long long)row * ldc + col] = f2b(val);
        } else if constexpr (MODE == 1) {
          const int bb = row / npos, rr = row - bb * npos;
          const int Nc = (int)gridDim.x * 128;
          ((unsigned short*)C)[((long long)bb * Nc + col) * npos + rr] = f2b(val);
        } else {
          const long long idx = (long long)row * ldc + col;
          ((float*)C)[idx] = resid[idx] + val;
        }
      }
    }
  }
}

// ---------------------------------------------------------------------------
// LayerNorm over C=256, one row per block, fp32 in -> bf16 out
// ---------------------------------------------------------------------------
__global__ __launch_bounds__(256) void ln_bf16(const float* __restrict__ x,
                                               const float* __restrict__ gamma,
                                               const float* __restrict__ beta,
                                               unsigned short* __restrict__ h)
{
  const long long row = blockIdx.x;
  const float* xr = x + row * 256;
  const int t = threadIdx.x;
  const float v = xr[t];
  float s = wred_add(v);
  float s2 = wred_add(v * v);
  __shared__ float red[8];
  const int w = t >> 6, lane = t & 63;
  if (lane == 0) { red[w] = s; red[4 + w] = s2; }
  __syncthreads();
  s = red[0] + red[1] + red[2] + red[3];
  s2 = red[4] + red[5] + red[6] + red[7];
  const float mean = s * (1.f / 256.f);
  const float var = s2 * (1.f / 256.f) - mean * mean;
  const float rstd = rsqrtf(var + 1e-3f);
  h[row * 256 + t] = f2b((v - mean) * rstd * gamma[t] + beta[t]);
}

// ---------------------------------------------------------------------------
// Transpose + bf16-cast the four 256x256 weights
// ---------------------------------------------------------------------------
__global__ void wtrans(const float* __restrict__ wq, const float* __restrict__ wk,
                       const float* __restrict__ wv, const float* __restrict__ wo,
                       unsigned short* __restrict__ wT)
{
  const float* w = blockIdx.z == 0 ? wq : blockIdx.z == 1 ? wk : blockIdx.z == 2 ? wv : wo;
  unsigned short* o = wT + (long long)blockIdx.z * 65536;
  __shared__ float tile[16][17];
  const int tx = threadIdx.x, ty = threadIdx.y;
  const int bx = blockIdx.x * 16, by = blockIdx.y * 16;
  tile[ty][tx] = w[(by + ty) * 256 + bx + tx];
  __syncthreads();
  o[(bx + ty) * 256 + (by + tx)] = f2b(tile[tx][ty]);
}

// ---------------------------------------------------------------------------
// Fused flash attention. grid (32 qblocks, 8 batches), 256 thr = 4 waves.
// Wave owns 32 q-rows. KVBLK=64, K/V double-buffered in dynamic LDS (144KB):
//   Ks[2]: 2x32KB @0, Vs[2]: 2x32KB @64KB, P slabs: 4x4KB @128KB.
// All LDS tiles XOR-swizzled: byte ^= ((row&7)<<4); staging achieves the
// swizzle by pre-swizzling the per-lane GLOBAL source (linear LDS dest).
// Q (pre-scaled by log2e/sqrt(C)) held in registers. Softmax in exp2 domain.
// ---------------------------------------------------------------------------
#define FL_LDS (144 * 1024)

__global__ __launch_bounds__(256) void flash(
    const unsigned short* __restrict__ q,   // [B][4096][256] bf16 (scaled)
    const unsigned short* __restrict__ kk,  // [B][4096][256] bf16
    const unsigned short* __restrict__ vT,  // [B][256][4096] bf16
    unsigned short* __restrict__ oo)        // [B][4096][256] bf16
{
  extern __shared__ char lds[];
  const int t = threadIdx.x;
  const int w = t >> 6;
  const int lane = t & 63;
  const int l15 = lane & 15, l4 = lane >> 4;
  const int b = blockIdx.y;
  const long long qrow = (long long)b * 4096 + (long long)blockIdx.x * 128 + w * 32;

  const unsigned short* kbase = kk + (long long)b * 4096 * 256;
  const unsigned short* vbase = vT + (long long)b * 256 * 4096;

  // staging source bases (pre-swizzled). For instr p:
  //  K: row = p*8 + (t>>5), granule g = (t&31)^((t>>5)&7)   (512B rows)
  //  V: row d = p*32 + (t>>3), granule g = (t&7)^((t>>3)&7) (128B rows)
  const int gs_k = (t & 31) ^ ((t >> 5) & 7);
  const unsigned short* Kst = kbase + (t >> 5) * 256 + gs_k * 8;
  const int gs_v = (t & 7) ^ ((t >> 3) & 7);
  const unsigned short* Vst = vbase + (long long)(t >> 3) * 4096 + gs_v * 8;
  char* const kd0 = lds + w * 1024;            // wave-uniform LDS dests
  char* const vd0 = lds + 65536 + w * 1024;
  char* const Pw = lds + 131072 + w * 4096;    // wave-private P [32][64] bf16

  // Q fragments, persistent: Qf[i][ks] covers rows w*32+i*16+l15, k=ks*32+l4*8
  bf16x8 Qf[2][8];
  {
    const unsigned short* qp = q + (qrow + l15) * 256 + l4 * 8;
#pragma unroll
    for (int i = 0; i < 2; i++)
#pragma unroll
      for (int ks = 0; ks < 8; ks++)
        Qf[i][ks] = *(const bf16x8*)(qp + i * 16 * 256 + ks * 32);
  }

  f32x4 O[2][16] = {};
  float mrow[2][4], lrow[2][4];
#pragma unroll
  for (int i = 0; i < 2; i++)
#pragma unroll
    for (int r = 0; r < 4; r++) { mrow[i][r] = -1e30f; lrow[i][r] = 0.f; }

  // prologue: stage tile 0 -> buf 0
#pragma unroll
  for (int p = 0; p < 8; p++) {
    glds16(Kst + p * 2048, kd0 + p * 4096);
    glds16(Vst + (long long)p * 32 * 4096, vd0 + p * 4096);
  }

  for (int it = 0; it < 64; ++it) {
    const int cur = it & 1;
    __syncthreads();  // buf[cur] staged (vmcnt drained), buf[cur^1] free
    if (it < 63) {
      const unsigned short* ks_ = Kst + (it + 1) * 16384;
      const unsigned short* vs_ = Vst + (it + 1) * 64;
      char* kd = kd0 + (cur ^ 1) * 32768;
      char* vd = vd0 + (cur ^ 1) * 32768;
#pragma unroll
      for (int p = 0; p < 8; p++) {
        glds16(ks_ + p * 2048, kd + p * 4096);
        glds16(vs_ + (long long)p * 32 * 4096, vd + p * 4096);
      }
    }
    const char* Kb = lds + cur * 32768;
    const char* Vb = lds + 65536 + cur * 32768;

    // S = Q K^T   (S[i][j]: rows i*16+l4*4+r, cols j*16+l15)
    f32x4 S[2][4] = {};
#pragma unroll
    for (int ks = 0; ks < 8; ks++) {
#pragma unroll
      for (int j = 0; j < 4; j++) {
        const int key = j * 16 + l15;
        bf16x8 Kf = *(const bf16x8*)(Kb + key * 512 +
                                     ((ks * 64 + l4 * 16) ^ ((l15 & 7) << 4)));
#pragma unroll
        for (int i = 0; i < 2; i++)
          S[i][j] = __builtin_amdgcn_mfma_f32_16x16x32_bf16(Qf[i][ks], Kf, S[i][j], 0, 0, 0);
      }
    }

    // online softmax (base-2 domain; scale folded into q)
#pragma unroll
    for (int i = 0; i < 2; i++) {
#pragma unroll
      for (int r = 0; r < 4; r++) {
        float mx = fmaxf(fmaxf(S[i][0][r], S[i][1][r]), fmaxf(S[i][2][r], S[i][3][r]));
#pragma unroll
        for (int msk = 1; msk <= 8; msk <<= 1) mx = fmaxf(mx, __shfl_xor(mx, msk, 64));
        const float mn = fmaxf(mrow[i][r], mx);
        const float rs_ = exp2f(mrow[i][r] - mn);
        mrow[i][r] = mn;
        float sum = 0.f;
#pragma unroll
        for (int j = 0; j < 4; j++) {
          const float e = exp2f(S[i][j][r] - mn);
          S[i][j][r] = e;
          sum += e;
        }
#pragma unroll
        for (int msk = 1; msk <= 8; msk <<= 1) sum += __shfl_xor(sum, msk, 64);
        lrow[i][r] = lrow[i][r] * rs_ + sum;
#pragma unroll
        for (int jd = 0; jd < 16; jd++) O[i][jd][r] *= rs_;
      }
    }

    // write P (bf16, swizzled) to wave-private slab
#pragma unroll
    for (int i = 0; i < 2; i++)
#pragma unroll
      for (int j = 0; j < 4; j++)
#pragma unroll
        for (int r = 0; r < 4; r++) {
          const int row = i * 16 + l4 * 4 + r;
          *(unsigned short*)(Pw + row * 128 +
                             (((j * 16 + l15) * 2) ^ ((row & 7) << 4))) = f2b(S[i][j][r]);
        }

    // PV: O += P * V^T
    bf16x8 Pf[2][2];
#pragma unroll
    for (int i = 0; i < 2; i++)
#pragma unroll
      for (int ks = 0; ks < 2; ks++) {
        const int qr = i * 16 + l15;
        Pf[i][ks] = *(const bf16x8*)(Pw + qr * 128 +
                                     ((ks * 64 + l4 * 16) ^ ((qr & 7) << 4)));
      }
#pragma unroll
    for (int ks = 0; ks < 2; ks++)
#pragma unroll
      for (int jd = 0; jd < 16; jd++) {
        const int d = jd * 16 + l15;
        bf16x8 Vf = *(const bf16x8*)(Vb + d * 128 +
                                     ((ks * 64 + l4 * 16) ^ ((d & 7) << 4)));
#pragma unroll
        for (int i = 0; i < 2; i++)
          O[i][jd] = __builtin_amdgcn_mfma_f32_16x16x32_bf16(Pf[i][ks], Vf, O[i][jd], 0, 0, 0);
      }
  }

  // epilogue: O /= l, write bf16
#pragma unroll
  for (int i = 0; i < 2; i++) {
    float inv[4];
#pragma unroll
    for (int r = 0; r < 4; r++) inv[r] = 1.f / lrow[i][r];
#pragma unroll
    for (int jd = 0; jd < 16; jd++)
#pragma unroll
      for (int r = 0; r < 4; r++) {
        const long long row = qrow + i * 16 + l4 * 4 + r;
        oo[row * 256 + jd * 16 + l15] = f2b(O[i][jd][r] * inv[r]);
      }
  }
}

// ---------------------------------------------------------------------------
extern "C" void kernel_launch(void* const* d_in, const int* in_sizes, int n_in,
                              void* d_out, int out_size, void* d_ws, size_t ws_size,
                              hipStream_t stream)
{
  const float* x = (const float*)d_in[0];
  const float* gamma = (const float*)d_in[1];
  const float* beta = (const float*)d_in[2];
  const float* wq = (const float*)d_in[3];
  const float* bq = (const float*)d_in[4];
  const float* wk = (const float*)d_in[5];
  const float* bk = (const float*)d_in[6];
  const float* wv = (const float*)d_in[7];
  const float* bv = (const float*)d_in[8];
  const float* wo = (const float*)d_in[9];
  const float* bo = (const float*)d_in[10];

  const int Cc = 256, Np = 4096, Bn = 8;
  const long long MR = (long long)Bn * Np;  // 32768

  char* base = (char*)d_ws;
  size_t off = 0;
  auto take = [&](size_t bytes) -> char* {
    char* p = base + off;
    off = (off + bytes + 255) & ~(size_t)255;
    return p;
  };
  unsigned short* h  = (unsigned short*)take((size_t)MR * Cc * 2);
  unsigned short* q  = (unsigned short*)take((size_t)MR * Cc * 2);  // scaled
  unsigned short* kk = (unsigned short*)take((size_t)MR * Cc * 2);
  unsigned short* vT = (unsigned short*)take((size_t)MR * Cc * 2);  // [B][C][Np]
  unsigned short* oo = (unsigned short*)take((size_t)MR * Cc * 2);
  unsigned short* wT = (unsigned short*)take(4ull * Cc * Cc * 2);

  wtrans<<<dim3(16, 16, 4), dim3(16, 16), 0, stream>>>(wq, wk, wv, wo, wT);
  ln_bf16<<<dim3((unsigned)MR), dim3(256), 0, stream>>>(x, gamma, beta, h);

  // Q = (h@wq + bq) * log2e/sqrt(C) ; K = h@wk + bk ; V transposed per batch
  const float qscale = 0.0625f * 1.44269504f;
  gemm_nt<0><<<dim3(2, 256, 1), 256, 0, stream>>>(h, Cc, 0, wT + 0 * 65536, Cc, 0,
                                                  q, Cc, 0, Cc, bq, qscale, nullptr, 0);
  gemm_nt<0><<<dim3(2, 256, 1), 256, 0, stream>>>(h, Cc, 0, wT + 1 * 65536, Cc, 0,
                                                  kk, Cc, 0, Cc, bk, 1.0f, nullptr, 0);
  gemm_nt<1><<<dim3(2, 256, 1), 256, 0, stream>>>(h, Cc, 0, wT + 2 * 65536, Cc, 0,
                                                  vT, 0, 0, Cc, bv, 1.0f, nullptr, Np);

  flash<<<dim3(32, Bn), dim3(256), FL_LDS, stream>>>(q, kk, vT, oo);

  // out = x + oo@wo + bo
  gemm_nt<3><<<dim3(2, 256, 1), 256, 0, stream>>>(oo, Cc, 0, wT + 3 * 65536, Cc, 0,
                                                  (float*)d_out, Cc, 0, Cc, bo, 1.0f, x, 0);
}